// Round 1
// 604.494 us; speedup vs baseline: 1.0289x; 1.0289x over previous
//
#include <hip/hip_runtime.h>

// NeuralODE: z0 = enc(y0); 100 x Tsit5 steps of f = W3 tanh(W2 tanh(W1 y + b1) + b2) + b3;
// outputs ys = dec(z_t), zs = z_t.  One wave (64 thr) per 16 batch elements, grid 256.
//
// GEMM orientation: D[row, elem] = W[row, k] * Act[k, elem] with mfma_f32_16x16x32_f16.
// Lane l = (e = l&15, q = l>>4). C/D: lane holds rows p = 16t+4q+r (t = M-tile, r = reg).
// Consumer weight k-columns are pre-shuffled by kappa so that the producer's C/D registers
// ARE the consumer's lane-local B-fragment (see load_wfrag slot mapping).
// 3-term f16 hi/lo split (Whi*Bhi + Wlo*Bhi + Whi*Blo) keeps per-product error ~2^-22.
//
// This revision (latency-bound, 1 wave/SIMD, no TLP -> ILP only):
//  - decoder frags live in VGPRs (LDS + in-loop ds_read/lgkm waits removed entirely)
//  - stores + decode of state s-1 deferred until after evalf(z,k1) is issued: the 8 dec
//    MFMAs + 8 global stores are the only independent work available to fill the serial
//    k-chain's dependency bubbles
//  - tanh input scale 2/ln2 folded into W1,b1,W2,b2 at load; dt folded into all Butcher
//    coefficients; stage combos restructured as running accumulators so each k_i dies
//    immediately (shrinks live set, kills AGPR parking round-trips)

typedef __attribute__((ext_vector_type(8))) _Float16 half8;
typedef __attribute__((ext_vector_type(4))) float f32x4;

static constexpr int TN = 101;
static constexpr int BN = 4096;

#define MFMA(a, b, c) __builtin_amdgcn_mfma_f32_16x16x32_f16((a), (b), (c), 0, 0, 0)

__device__ __forceinline__ float tanh_pre(float x) {
  // input already scaled by 2/ln2: tanh = 1 - 2/(1+2^x); exact at +/-inf via exp2 range.
  float e = __builtin_amdgcn_exp2f(x);
  float r = __builtin_amdgcn_rcpf(e + 1.0f);
  return __builtin_fmaf(-2.0f, r, 1.0f);
}

__device__ __forceinline__ void split8(const float* v, half8& hi, half8& lo) {
#pragma unroll
  for (int j = 0; j < 8; ++j) {
    _Float16 h = (_Float16)v[j];
    hi[j] = h;
    lo[j] = (_Float16)(v[j] - (float)h);
  }
}

// A-fragment for a weight whose k-columns are consumed kappa-shuffled:
// slot j of lane q, K-tile kt  <-  W[row][kt*32 + 16*(j>>2) + 4*q + (j&3)] * scale
__device__ __forceinline__ void load_wfrag(const float* __restrict__ W, int C, int row, int q,
                                           int kt, float scale, half8& hi, half8& lo) {
  const float* p = W + row * C + kt * 32 + 4 * q;
  float v[8] __attribute__((aligned(16)));
  *(f32x4*)(v) = *(const f32x4*)(p);
  *(f32x4*)(v + 4) = *(const f32x4*)(p + 16);
#pragma unroll
  for (int j = 0; j < 8; ++j) v[j] *= scale;
  split8(v, hi, lo);
}

__global__ __launch_bounds__(64, 1) void node_kernel(
    const float* __restrict__ ts, const float* __restrict__ y0,
    const float* __restrict__ encW, const float* __restrict__ encb,
    const float* __restrict__ W1, const float* __restrict__ b1,
    const float* __restrict__ W2, const float* __restrict__ b2,
    const float* __restrict__ W3, const float* __restrict__ b3,
    const float* __restrict__ decW, const float* __restrict__ decb,
    float* __restrict__ out) {
  const int l = threadIdx.x;
  const int lm = l & 15;
  const int q = l >> 4;
  const int eg = blockIdx.x * 16 + lm;

  const float TS = 2.8853900817779268f;  // 2/ln2, folded into W1,b1,W2,b2

  // ---- persistent MLP weight fragments (f16 hi+lo) ----
  half8 w1h[2][2], w1l[2][2], w2h[2], w2l[2], w3h[4], w3l[4];
#pragma unroll
  for (int mt = 0; mt < 2; ++mt) {
#pragma unroll
    for (int kt = 0; kt < 2; ++kt)
      load_wfrag(W1, 64, 16 * mt + lm, q, kt, TS, w1h[mt][kt], w1l[mt][kt]);
    load_wfrag(W2, 32, 16 * mt + lm, q, 0, TS, w2h[mt], w2l[mt]);
  }
#pragma unroll
  for (int mt = 0; mt < 4; ++mt) load_wfrag(W3, 32, 16 * mt + lm, q, 0, 1.0f, w3h[mt], w3l[mt]);

  f32x4 b1f[2], b2f[2], b3f[4];
#pragma unroll
  for (int mt = 0; mt < 2; ++mt) {
    f32x4 t1 = *(const f32x4*)(b1 + 16 * mt + 4 * q);
    f32x4 t2 = *(const f32x4*)(b2 + 16 * mt + 4 * q);
#pragma unroll
    for (int r = 0; r < 4; ++r) {
      t1[r] *= TS;
      t2[r] *= TS;
    }
    b1f[mt] = t1;
    b2f[mt] = t2;
  }
#pragma unroll
  for (int mt = 0; mt < 4; ++mt) b3f[mt] = *(const f32x4*)(b3 + 16 * mt + 4 * q);

  // ---- decoder frags in REGISTERS (single f16: decoder error does not feed back) ----
  half8 dech[4][2];
  f32x4 decbf[4];
#pragma unroll
  for (int mt = 0; mt < 4; ++mt) {
#pragma unroll
    for (int kt = 0; kt < 2; ++kt) {
      const float* p = decW + (16 * mt + lm) * 64 + kt * 32 + 4 * q;
      float v[8] __attribute__((aligned(16)));
      *(f32x4*)(v) = *(const f32x4*)(p);
      *(f32x4*)(v + 4) = *(const f32x4*)(p + 16);
      half8 h;
#pragma unroll
      for (int j = 0; j < 8; ++j) h[j] = (_Float16)v[j];
      dech[mt][kt] = h;
    }
    decbf[mt] = *(const f32x4*)(decb + 16 * mt + 4 * q);
  }

  float z[16];

  // ---- encoder: z0 = encW * y0^T + encb (enc cols in TRUE order; y0 frag = 8 consecutive) ----
  {
    const float* yp = y0 + (size_t)eg * 64;
    float v[16] __attribute__((aligned(16)));
    *(f32x4*)(v) = *(const f32x4*)(yp + 8 * q);
    *(f32x4*)(v + 4) = *(const f32x4*)(yp + 8 * q + 4);
    *(f32x4*)(v + 8) = *(const f32x4*)(yp + 32 + 8 * q);
    *(f32x4*)(v + 12) = *(const f32x4*)(yp + 32 + 8 * q + 4);
    half8 xh[2], xl[2];
    split8(v, xh[0], xl[0]);
    split8(v + 8, xh[1], xl[1]);
#pragma unroll
    for (int mt = 0; mt < 4; ++mt) {
      const float* p0 = encW + (16 * mt + lm) * 64 + 8 * q;
      float w[8] __attribute__((aligned(16)));
      half8 eh, el;
      f32x4 a = *(const f32x4*)(encb + 16 * mt + 4 * q);
      *(f32x4*)(w) = *(const f32x4*)(p0);
      *(f32x4*)(w + 4) = *(const f32x4*)(p0 + 4);
      split8(w, eh, el);
      a = MFMA(eh, xh[0], a);
      a = MFMA(el, xh[0], a);
      a = MFMA(eh, xl[0], a);
      *(f32x4*)(w) = *(const f32x4*)(p0 + 32);
      *(f32x4*)(w + 4) = *(const f32x4*)(p0 + 36);
      split8(w, eh, el);
      a = MFMA(eh, xh[1], a);
      a = MFMA(el, xh[1], a);
      a = MFMA(eh, xl[1], a);
#pragma unroll
      for (int r = 0; r < 4; ++r) z[4 * mt + r] = a[r];
    }
  }

  // ---- helpers ----
  auto evalf = [&](const float (&yv)[16], float (&kv)[16]) {
    half8 yh[2], yl[2];
    split8(yv, yh[0], yl[0]);
    split8(yv + 8, yh[1], yl[1]);
    float h1[8], h2[8];
#pragma unroll
    for (int mt = 0; mt < 2; ++mt) {
      f32x4 a = b1f[mt];
      a = MFMA(w1h[mt][0], yh[0], a);
      a = MFMA(w1l[mt][0], yh[0], a);
      a = MFMA(w1h[mt][0], yl[0], a);
      a = MFMA(w1h[mt][1], yh[1], a);
      a = MFMA(w1l[mt][1], yh[1], a);
      a = MFMA(w1h[mt][1], yl[1], a);
#pragma unroll
      for (int r = 0; r < 4; ++r) h1[4 * mt + r] = tanh_pre(a[r]);
    }
    half8 hh, hl;
    split8(h1, hh, hl);
#pragma unroll
    for (int mt = 0; mt < 2; ++mt) {
      f32x4 a = b2f[mt];
      a = MFMA(w2h[mt], hh, a);
      a = MFMA(w2l[mt], hh, a);
      a = MFMA(w2h[mt], hl, a);
#pragma unroll
      for (int r = 0; r < 4; ++r) h2[4 * mt + r] = tanh_pre(a[r]);
    }
    split8(h2, hh, hl);
#pragma unroll
    for (int mt = 0; mt < 4; ++mt) {
      f32x4 a = b3f[mt];
      a = MFMA(w3h[mt], hh, a);
      a = MFMA(w3l[mt], hh, a);
      a = MFMA(w3h[mt], hl, a);
#pragma unroll
      for (int r = 0; r < 4; ++r) kv[4 * mt + r] = a[r];
    }
  };

  auto store_z = [&](const float (&x)[16], int s) {
    float* zb = out + (size_t)BN * TN * 64 + ((size_t)eg * TN + s) * 64;
#pragma unroll
    for (int t = 0; t < 4; ++t) {
      f32x4 v = {x[4 * t], x[4 * t + 1], x[4 * t + 2], x[4 * t + 3]};
      *(f32x4*)(zb + 16 * t + 4 * q) = v;  // row p = 16t+4q+r, true dim order
    }
  };

  auto dec_store = [&](const float (&x)[16], int s) {
    half8 xh[2];
#pragma unroll
    for (int j = 0; j < 8; ++j) {
      xh[0][j] = (_Float16)x[j];
      xh[1][j] = (_Float16)x[8 + j];
    }
    float* yb = out + ((size_t)eg * TN + s) * 64;
#pragma unroll
    for (int mt = 0; mt < 4; ++mt) {
      f32x4 a = decbf[mt];
      a = MFMA(dech[mt][0], xh[0], a);
      a = MFMA(dech[mt][1], xh[1], a);
      *(f32x4*)(yb + 16 * mt + 4 * q) = a;
    }
  };

  // ---- dt-folded Butcher coefficients (wave-uniform scalars) ----
  const float dt = (ts[TN - 1] - ts[0]) / (float)(TN - 1);
  const float c21 = dt * 0.161f;
  const float c31 = dt * -0.008480655492356989f, c32 = dt * 0.335480655492357f;
  const float c41 = dt * 2.8971530571054935f, c42 = dt * -6.359448489975075f,
              c43 = dt * 4.3622954328695815f;
  const float c51 = dt * 5.325864828439257f, c52 = dt * -11.748883564062828f,
              c53 = dt * 7.4955393428898365f, c54 = dt * -0.09249506636175525f;
  const float c61 = dt * 5.86145544294642f, c62 = dt * -12.92096931784711f,
              c63 = dt * 8.159367898576159f, c64 = dt * -0.071584973281401f,
              c65 = dt * -0.028269050394068383f;
  const float d1 = dt * 0.09646076681806523f, d2 = dt * 0.01f, d3 = dt * 0.4798896504144996f,
              d4 = dt * 1.379008574103742f, d5 = dt * -3.290069515436081f,
              d6 = dt * 2.324710524099774f;

#pragma nounroll
  for (int s = 1; s < TN; ++s) {
    float k[16], y2[16], y3[16], y4[16], y5[16], y6[16], zn[16];
    evalf(z, k);  // k1 (issued first so the deferred stores below fill its bubbles)
    store_z(z, s - 1);   // state s-1: independent of the k-chain, free MFMA-pipe filler
    dec_store(z, s - 1);
#pragma unroll
    for (int i = 0; i < 16; ++i) {
      y2[i] = __builtin_fmaf(c21, k[i], z[i]);
      y3[i] = __builtin_fmaf(c31, k[i], z[i]);
      y4[i] = __builtin_fmaf(c41, k[i], z[i]);
      y5[i] = __builtin_fmaf(c51, k[i], z[i]);
      y6[i] = __builtin_fmaf(c61, k[i], z[i]);
      zn[i] = __builtin_fmaf(d1, k[i], z[i]);
    }
    evalf(y2, k);  // k2
#pragma unroll
    for (int i = 0; i < 16; ++i) {
      y3[i] = __builtin_fmaf(c32, k[i], y3[i]);
      y4[i] = __builtin_fmaf(c42, k[i], y4[i]);
      y5[i] = __builtin_fmaf(c52, k[i], y5[i]);
      y6[i] = __builtin_fmaf(c62, k[i], y6[i]);
      zn[i] = __builtin_fmaf(d2, k[i], zn[i]);
    }
    evalf(y3, k);  // k3
#pragma unroll
    for (int i = 0; i < 16; ++i) {
      y4[i] = __builtin_fmaf(c43, k[i], y4[i]);
      y5[i] = __builtin_fmaf(c53, k[i], y5[i]);
      y6[i] = __builtin_fmaf(c63, k[i], y6[i]);
      zn[i] = __builtin_fmaf(d3, k[i], zn[i]);
    }
    evalf(y4, k);  // k4
#pragma unroll
    for (int i = 0; i < 16; ++i) {
      y5[i] = __builtin_fmaf(c54, k[i], y5[i]);
      y6[i] = __builtin_fmaf(c64, k[i], y6[i]);
      zn[i] = __builtin_fmaf(d4, k[i], zn[i]);
    }
    evalf(y5, k);  // k5
#pragma unroll
    for (int i = 0; i < 16; ++i) {
      y6[i] = __builtin_fmaf(c65, k[i], y6[i]);
      zn[i] = __builtin_fmaf(d5, k[i], zn[i]);
    }
    evalf(y6, k);  // k6
#pragma unroll
    for (int i = 0; i < 16; ++i) z[i] = __builtin_fmaf(d6, k[i], zn[i]);
  }
  store_z(z, TN - 1);
  dec_store(z, TN - 1);
}

extern "C" void kernel_launch(void* const* d_in, const int* in_sizes, int n_in,
                              void* d_out, int out_size, void* d_ws, size_t ws_size,
                              hipStream_t stream) {
  const float* ts = (const float*)d_in[0];
  const float* y0 = (const float*)d_in[1];
  const float* encW = (const float*)d_in[2];
  const float* encb = (const float*)d_in[3];
  const float* W1 = (const float*)d_in[4];
  const float* b1 = (const float*)d_in[5];
  const float* W2 = (const float*)d_in[6];
  const float* b2 = (const float*)d_in[7];
  const float* W3 = (const float*)d_in[8];
  const float* b3 = (const float*)d_in[9];
  const float* decW = (const float*)d_in[10];
  const float* decb = (const float*)d_in[11];
  node_kernel<<<BN / 16, 64, 0, stream>>>(ts, y0, encW, encb, W1, b1, W2, b2, W3, b3, decW, decb,
                                          (float*)d_out);
}